// Round 1
// baseline (1283.845 us; speedup 1.0000x reference)
//
#include <hip/hip_runtime.h>
#include <hip/hip_bf16.h>

// Problem constants
#define NB   1000
#define TT   15
#define PP   5
#define CI   32
#define CO   32
#define KDIM 9600      // 2 complex * (1+2+3+4)=10 comps * 15 t * 32 cin
#define MDIM 640       // 2 complex * 10 comps * 32 cout
#define NCHUNK 300     // KDIM/32
#define NCOL   20      // MDIM/32
#define TABN  16384    // 4 combos * 4^6

// ---------------- compile-time integer maps ----------------
struct Chunks { short ci[NCHUNK]; short l2[NCHUNK]; short t[NCHUNK]; short k2[NCHUNK]; };
constexpr Chunks mkchunks() {
  Chunks c{};
  int idx = 0;
  for (int l2 = 0; l2 < 4; ++l2)
    for (int ci = 0; ci < 2; ++ci)
      for (int t = 0; t < TT; ++t)
        for (int k2 = 0; k2 <= l2; ++k2) {
          c.ci[idx] = (short)ci; c.l2[idx] = (short)l2;
          c.t[idx] = (short)t;   c.k2[idx] = (short)k2; ++idx;
        }
  return c;
}
__constant__ Chunks g_ck = mkchunks();

struct Cols { int l[NCOL]; int lm[NCOL]; int ci[NCOL]; long obase[NCOL]; };
constexpr Cols mkcols() {
  Cols c{};
  long acc = 0; int idx = 0;
  for (int l = 0; l < 4; ++l)
    for (int ci = 0; ci < 2; ++ci) {
      for (int lm = 0; lm <= l; ++lm) {
        c.l[idx] = l; c.lm[idx] = lm; c.ci[idx] = ci; c.obase[idx] = acc; ++idx;
      }
      acc += (long)NB * (l + 1) * PP * CO;
    }
  return c;
}
__constant__ Cols g_cols = mkcols();

// ---------------- device CG (Racah) in fp64 ----------------
__device__ double dfact(int n) { double r = 1.0; for (int i = 2; i <= n; ++i) r *= i; return r; }

__device__ double dcg(int j1, int m1, int j2, int m2, int J, int M) {
  if (m1 + m2 != M) return 0.0;
  int lo = j1 - j2; if (lo < 0) lo = -lo;
  if (J < lo || J > j1 + j2) return 0.0;
  int am1 = m1 < 0 ? -m1 : m1, am2 = m2 < 0 ? -m2 : m2, aM = M < 0 ? -M : M;
  if (am1 > j1 || am2 > j2 || aM > J) return 0.0;
  double pre = (2.0 * J + 1.0) * dfact(J + j1 - j2) * dfact(J - j1 + j2) * dfact(j1 + j2 - J)
               / dfact(j1 + j2 + J + 1);
  pre *= dfact(J + M) * dfact(J - M) * dfact(j1 - m1) * dfact(j1 + m1) * dfact(j2 - m2) * dfact(j2 + m2);
  double s = 0.0;
  for (int k = 0; k <= j1 + j2 - J; ++k) {
    int d1 = j1 + j2 - J - k, d2 = j1 - m1 - k, d3 = j2 + m2 - k,
        d4 = J - j2 + m1 + k, d5 = J - j1 - m2 + k;
    if (d1 < 0 || d2 < 0 || d3 < 0 || d4 < 0 || d5 < 0) continue;
    double den = dfact(k) * dfact(d1) * dfact(d2) * dfact(d3) * dfact(d4) * dfact(d5);
    s += ((k & 1) ? -1.0 : 1.0) / den;
  }
  return sqrt(pre) * s;
}

// tab[combo][l][l1][l2][lm][m][k2], combos: 0 = xr*wr->out_r, 1 = xi*wi->out_r,
//                                           2 = xr*wi->out_i, 3 = xi*wr->out_i
__global__ void k_tables(float* __restrict__ tab) {
  int idx = blockIdx.x * blockDim.x + threadIdx.x;
  if (idx >= TABN) return;
  int k2 = idx & 3, m = (idx >> 2) & 3, lm = (idx >> 4) & 3, l2 = (idx >> 6) & 3,
      l1 = (idx >> 8) & 3, l = (idx >> 10) & 3, combo = (idx >> 12) & 3;
  float v = 0.f;
  int dlo = l - l1; if (dlo < 0) dlo = -dlo;
  bool valid = (lm <= l) && (m <= l1) && (k2 <= l2) && (l2 >= dlo) && (l2 <= l + l1);
  if (valid) {
    const double PI = 3.14159265358979323846;
    double coef = 8.0 * PI * PI / (2.0 * l1 + 1.0)
                  * sqrt((2.0 * l + 1.0) * (2.0 * l1 + 1.0) / (4.0 * PI * (2.0 * l2 + 1.0)))
                  * dcg(l, 0, l1, 0, l2, 0);
    double t1 = 0.0, t2 = 0.0, t3 = 0.0;
    if (k2 == lm + m)
      t1 = dcg(l, lm, l1, m, l2, k2) * ((m & 1) ? -1.0 : 1.0);
    if (m > 0 && lm - m >= 0 && k2 == lm - m)
      t2 = dcg(l, lm, l1, -m, l2, lm - m) * ((l1 & 1) ? -1.0 : 1.0);
    if (m > 0 && lm - m < 0 && k2 == m - lm)
      t3 = (((m - lm) & 1) ? -1.0 : 1.0) * (((l1 + l2) & 1) ? -1.0 : 1.0)
           * dcg(l, lm, l1, -m, l2, lm - m);
    double r = 0.0;
    if (combo == 0) r =  coef * (t1 + t2 + t3);
    else if (combo == 1) r = -coef * (t1 - t2 + t3);
    else if (combo == 2) r =  coef * (t1 - t2 - t3);
    else r = coef * (t1 + t2 - t3);
    v = (float)r;
  }
  tab[idx] = v;
}

// ---------------- fold: W_eff[p][K][M] ----------------
struct FArgs { const float* w[8]; const float* tab; float* weff; };

__global__ __launch_bounds__(640) void k_fold(FArgs A) {
  int kk = blockIdx.x;        // 0..9599
  int p  = blockIdx.y;        // 0..4
  int mo = threadIdx.x;       // 0..639
  int chunk = kk >> 5, i = kk & 31;
  int ci_in = g_ck.ci[chunk], l2 = g_ck.l2[chunk], t = g_ck.t[chunk], k2 = g_ck.k2[chunk];
  int j = mo & 31, col = mo >> 5;
  int l = g_cols.l[col], lm = g_cols.lm[col], ci_out = g_cols.ci[col];
  int combo = ci_out * 2 + ci_in;                 // 0=rr 1=ri 2=ir 3=ii
  int wci = (combo == 1 || combo == 2) ? 1 : 0;   // these pair with imag weights
  float s = 0.f;
  #pragma unroll
  for (int l1 = 0; l1 < 4; ++l1) {
    const float* w = A.w[2 * l1 + wci];
    for (int m = (wci ? 1 : 0); m <= l1; ++m) {   // wi row m=0 is masked to zero
      float cv = A.tab[(((((combo * 4 + l) * 4 + l1) * 4 + l2) * 4 + lm) * 4 + m) * 4 + k2];
      s += cv * w[(((m * TT + t) * PP + p) * CI + i) * CO + j];
    }
  }
  A.weff[((size_t)p * KDIM + kk) * MDIM + mo] = s;
}

// ---------------- GEMM: C[p] = X[p](1000x9600) * Weff[p](9600x640) ----------------
struct GArgs { const float* x[8]; const float* b[8]; const float* weff; float* out; };

__global__ __launch_bounds__(256) void k_gemm(GArgs A) {
  const int tid = threadIdx.x;
  const int n0  = blockIdx.x * 64;
  const int mo0 = blockIdx.y * 64;
  const int p   = blockIdx.z;
  __shared__ __align__(16) float sAT[32][68];  // [k][n] transposed, pad 68
  __shared__ __align__(16) float sB[32][68];   // [k][m]
  float acc[4][4] = {};
  const int tx = tid & 15, ty = tid >> 4;

  for (int cc = 0; cc < NCHUNK; ++cc) {
    const int l2 = g_ck.l2[cc], ci = g_ck.ci[cc], t = g_ck.t[cc], k2 = g_ck.k2[cc];
    const float* xp = A.x[2 * l2 + ci];
    const int ns  = TT * (l2 + 1) * PP * CI;                    // n stride
    const int off = ((t * (l2 + 1) + k2) * PP + p) * CI;        // within-n offset
    // load A tile (64 n x 32 k), store transposed
    #pragma unroll
    for (int u = 0; u < 2; ++u) {
      int f = tid + u * 256;            // 0..511 float4 slots
      int row = f >> 3;                 // n-local 0..63
      int c4  = (f & 7) * 4;            // k-local 0,4,..,28
      float4 v = make_float4(0.f, 0.f, 0.f, 0.f);
      int n = n0 + row;
      if (n < NB) v = *reinterpret_cast<const float4*>(xp + (size_t)n * ns + off + c4);
      sAT[c4 + 0][row] = v.x; sAT[c4 + 1][row] = v.y;
      sAT[c4 + 2][row] = v.z; sAT[c4 + 3][row] = v.w;
    }
    // load B tile (32 k x 64 m)
    const float* wp = A.weff + ((size_t)p * KDIM + (size_t)cc * 32) * MDIM + mo0;
    #pragma unroll
    for (int u = 0; u < 2; ++u) {
      int f = tid + u * 256;
      int row = f >> 4;                 // k-local 0..31
      int c4  = (f & 15) * 4;           // m-local 0,4,..,60
      float4 v = *reinterpret_cast<const float4*>(wp + (size_t)row * MDIM + c4);
      *reinterpret_cast<float4*>(&sB[row][c4]) = v;
    }
    __syncthreads();
    #pragma unroll 8
    for (int kk = 0; kk < 32; ++kk) {
      float4 av = *reinterpret_cast<const float4*>(&sAT[kk][ty * 4]);
      float4 bv = *reinterpret_cast<const float4*>(&sB[kk][tx * 4]);
      float a[4] = {av.x, av.y, av.z, av.w};
      float b[4] = {bv.x, bv.y, bv.z, bv.w};
      #pragma unroll
      for (int r = 0; r < 4; ++r)
        #pragma unroll
        for (int c = 0; c < 4; ++c)
          acc[r][c] += a[r] * b[c];
    }
    __syncthreads();
  }

  // epilogue: bias + scatter to the 8 output tensors
  #pragma unroll
  for (int r = 0; r < 4; ++r) {
    int n = n0 + ty * 4 + r;
    if (n >= NB) continue;
    #pragma unroll
    for (int c = 0; c < 4; ++c) {
      int mo  = mo0 + tx * 4 + c;
      int col = mo >> 5, j = mo & 31;
      int l = g_cols.l[col], lm = g_cols.lm[col], cio = g_cols.ci[col];
      long base = g_cols.obase[col];
      float bias = A.b[2 * l + cio][(lm * PP + p) * CO + j];
      if (cio == 1 && lm == 0) bias = 0.f;   // imag bias lm=0 masked
      A.out[base + (((size_t)n * (l + 1) + lm) * PP + p) * CO + j] = acc[r][c] + bias;
    }
  }
}

extern "C" void kernel_launch(void* const* d_in, const int* in_sizes, int n_in,
                              void* d_out, int out_size, void* d_ws, size_t ws_size,
                              hipStream_t stream) {
  float* tab  = (float*)d_ws;
  float* weff = tab + TABN;

  k_tables<<<dim3(TABN / 256), dim3(256), 0, stream>>>(tab);

  FArgs fa;
  for (int i = 0; i < 8; ++i) fa.w[i] = (const float*)d_in[8 + i];
  fa.tab = tab; fa.weff = weff;
  k_fold<<<dim3(KDIM, PP), dim3(640), 0, stream>>>(fa);

  GArgs ga;
  for (int i = 0; i < 8; ++i) ga.x[i] = (const float*)d_in[i];
  for (int i = 0; i < 8; ++i) ga.b[i] = (const float*)d_in[16 + i];
  ga.weff = weff; ga.out = (float*)d_out;
  k_gemm<<<dim3((NB + 63) / 64, MDIM / 64, PP), dim3(256), 0, stream>>>(ga);
}

// Round 2
// 483.276 us; speedup vs baseline: 2.6565x; 2.6565x over previous
//
#include <hip/hip_runtime.h>
#include <hip/hip_bf16.h>

#define NB   1000
#define TT   15
#define PP   5
#define CI   32
#define CO   32
#define KDIM 9600
#define MDIM 640
#define NCHUNK 300
#define NCOL   20
#define TABN  16384

typedef __attribute__((ext_vector_type(8))) short          bf16x8;
typedef __attribute__((ext_vector_type(8))) unsigned short ushort8;
typedef __attribute__((ext_vector_type(4))) float          f32x4;

// ---------------- compile-time integer maps ----------------
struct Chunks {
  short ci[NCHUNK]; short l2[NCHUNK]; short t[NCHUNK]; short k2[NCHUNK];
  short xidx[NCHUNK]; int ns[NCHUNK]; int offc[NCHUNK];
};
constexpr Chunks mkchunks() {
  Chunks c{};
  int idx = 0;
  for (int l2 = 0; l2 < 4; ++l2)
    for (int ci = 0; ci < 2; ++ci)
      for (int t = 0; t < TT; ++t)
        for (int k2 = 0; k2 <= l2; ++k2) {
          c.ci[idx] = (short)ci; c.l2[idx] = (short)l2;
          c.t[idx] = (short)t;   c.k2[idx] = (short)k2;
          c.xidx[idx] = (short)(2 * l2 + ci);
          c.ns[idx]   = TT * (l2 + 1) * PP * CI;
          c.offc[idx] = (t * (l2 + 1) + k2) * PP * CI;
          ++idx;
        }
  return c;
}
__constant__ Chunks g_ck = mkchunks();

struct Cols { int l[NCOL]; int lm[NCOL]; int ci[NCOL]; long obase[NCOL]; };
constexpr Cols mkcols() {
  Cols c{};
  long acc = 0; int idx = 0;
  for (int l = 0; l < 4; ++l)
    for (int ci = 0; ci < 2; ++ci) {
      for (int lm = 0; lm <= l; ++lm) {
        c.l[idx] = l; c.lm[idx] = lm; c.ci[idx] = ci; c.obase[idx] = acc; ++idx;
      }
      acc += (long)NB * (l + 1) * PP * CO;
    }
  return c;
}
__constant__ Cols g_cols = mkcols();

// per-weight-tensor element counts / offsets in the transposed buffer
constexpr int wtsize(int tensor) { return ((tensor >> 1) + 1) * TT * PP * CI * CO; }
struct WOffs { int off[8]; int sz[8]; };
constexpr WOffs mkwoffs() {
  WOffs w{}; int acc = 0;
  for (int i = 0; i < 8; ++i) { w.off[i] = acc; w.sz[i] = wtsize(i); acc += w.sz[i]; }
  return w;
}
__constant__ WOffs g_wo = mkwoffs();

// ---------------- device CG (Racah) in fp64 ----------------
__device__ double dfact(int n) { double r = 1.0; for (int i = 2; i <= n; ++i) r *= i; return r; }

__device__ double dcg(int j1, int m1, int j2, int m2, int J, int M) {
  if (m1 + m2 != M) return 0.0;
  int lo = j1 - j2; if (lo < 0) lo = -lo;
  if (J < lo || J > j1 + j2) return 0.0;
  int am1 = m1 < 0 ? -m1 : m1, am2 = m2 < 0 ? -m2 : m2, aM = M < 0 ? -M : M;
  if (am1 > j1 || am2 > j2 || aM > J) return 0.0;
  double pre = (2.0 * J + 1.0) * dfact(J + j1 - j2) * dfact(J - j1 + j2) * dfact(j1 + j2 - J)
               / dfact(j1 + j2 + J + 1);
  pre *= dfact(J + M) * dfact(J - M) * dfact(j1 - m1) * dfact(j1 + m1) * dfact(j2 - m2) * dfact(j2 + m2);
  double s = 0.0;
  for (int k = 0; k <= j1 + j2 - J; ++k) {
    int d1 = j1 + j2 - J - k, d2 = j1 - m1 - k, d3 = j2 + m2 - k,
        d4 = J - j2 + m1 + k, d5 = J - j1 - m2 + k;
    if (d1 < 0 || d2 < 0 || d3 < 0 || d4 < 0 || d5 < 0) continue;
    double den = dfact(k) * dfact(d1) * dfact(d2) * dfact(d3) * dfact(d4) * dfact(d5);
    s += ((k & 1) ? -1.0 : 1.0) / den;
  }
  return sqrt(pre) * s;
}

// tab[combo][l][l1][l2][lm][m][k2]; combos: 0 = xr*wr->r, 1 = xi*wi->r, 2 = xr*wi->i, 3 = xi*wr->i
__global__ void k_tables(float* __restrict__ tab) {
  int idx = blockIdx.x * blockDim.x + threadIdx.x;
  if (idx >= TABN) return;
  int k2 = idx & 3, m = (idx >> 2) & 3, lm = (idx >> 4) & 3, l2 = (idx >> 6) & 3,
      l1 = (idx >> 8) & 3, l = (idx >> 10) & 3, combo = (idx >> 12) & 3;
  float v = 0.f;
  int dlo = l - l1; if (dlo < 0) dlo = -dlo;
  bool valid = (lm <= l) && (m <= l1) && (k2 <= l2) && (l2 >= dlo) && (l2 <= l + l1);
  if (valid) {
    const double PI = 3.14159265358979323846;
    double coef = 8.0 * PI * PI / (2.0 * l1 + 1.0)
                  * sqrt((2.0 * l + 1.0) * (2.0 * l1 + 1.0) / (4.0 * PI * (2.0 * l2 + 1.0)))
                  * dcg(l, 0, l1, 0, l2, 0);
    double t1 = 0.0, t2 = 0.0, t3 = 0.0;
    if (k2 == lm + m)
      t1 = dcg(l, lm, l1, m, l2, k2) * ((m & 1) ? -1.0 : 1.0);
    if (m > 0 && lm - m >= 0 && k2 == lm - m)
      t2 = dcg(l, lm, l1, -m, l2, lm - m) * ((l1 & 1) ? -1.0 : 1.0);
    if (m > 0 && lm - m < 0 && k2 == m - lm)
      t3 = (((m - lm) & 1) ? -1.0 : 1.0) * (((l1 + l2) & 1) ? -1.0 : 1.0)
           * dcg(l, lm, l1, -m, l2, lm - m);
    double r = 0.0;
    if (combo == 0) r =  coef * (t1 + t2 + t3);
    else if (combo == 1) r = -coef * (t1 - t2 + t3);
    else if (combo == 2) r =  coef * (t1 - t2 - t3);
    else r = coef * (t1 + t2 - t3);
    v = (float)r;
  }
  tab[idx] = v;
}

// ---------------- weight transpose: (m,t,p,i,j) -> (m,p,j,t,i) ----------------
struct WTArgs { const float* w[8]; float* wt; };

__global__ __launch_bounds__(256) void k_wtr(WTArgs A) {
  int tensor = blockIdx.y;
  int sz = g_wo.sz[tensor];
  int e = blockIdx.x * blockDim.x + threadIdx.x;   // output-linear index
  if (e >= sz) return;
  int i = e & 31;
  int t = (e >> 5) % TT;
  int r = e / (32 * TT);
  int j = r & 31;
  int p = (r >> 5) % PP;
  int m = r / (32 * PP);
  A.wt[g_wo.off[tensor] + e] = A.w[tensor][(((m * TT + t) * PP + p) * CI + i) * CO + j];
}

// ---------------- fold: W_effT[p][mo][k] in bf16 ----------------
struct FArgs { const float* wt; const float* tab; unsigned short* weffT; };

__global__ __launch_bounds__(256) void k_fold(FArgs A) {
  int mo = blockIdx.x;      // 0..639
  int p  = blockIdx.y;      // 0..4
  int j = mo & 31, col = mo >> 5;
  int l = g_cols.l[col], lm = g_cols.lm[col], cio = g_cols.ci[col];
  unsigned short* dst = A.weffT + ((size_t)(p * MDIM + mo)) * KDIM;
  for (int kk = threadIdx.x; kk < KDIM; kk += 256) {
    int chunk = kk >> 5, i = kk & 31;
    int ci_in = g_ck.ci[chunk], t = g_ck.t[chunk], l2 = g_ck.l2[chunk], k2 = g_ck.k2[chunk];
    int combo = cio * 2 + ci_in;
    int wci = (combo == 1 || combo == 2) ? 1 : 0;
    float s = 0.f;
    #pragma unroll
    for (int l1 = 0; l1 < 4; ++l1) {
      const float* wtp = A.wt + g_wo.off[2 * l1 + wci] + ((p * CO + j) * TT + t) * CI + i;
      for (int m = (wci ? 1 : 0); m <= l1; ++m) {
        float cv = A.tab[(((((combo * 4 + l) * 4 + l1) * 4 + l2) * 4 + lm) * 4 + m) * 4 + k2];
        s += cv * wtp[m * (PP * CO * TT * CI)];
      }
    }
    unsigned u = __float_as_uint(s);
    u += 0x7fff + ((u >> 16) & 1);
    dst[kk] = (unsigned short)(u >> 16);
  }
}

// ---------------- GEMM: out[p] = X[p](1000x9600) * W_effT[p]^T, bf16 MFMA ----------------
struct GArgs { const float* x[8]; const float* b[8]; const unsigned short* weffT; float* out; };

__global__ __launch_bounds__(256) void k_gemm(GArgs A) {
  const int tid = threadIdx.x;
  const int n0  = blockIdx.x * 64;
  const int mo0 = blockIdx.y * 64;
  const int p   = blockIdx.z;
  __shared__ __align__(16) unsigned short sA[2][64][40];   // [buf][n][k], pad 40
  __shared__ __align__(16) unsigned short sB[2][64][40];   // [buf][mo][k]
  f32x4 acc[2][2] = {};

  const int lane = tid & 63;
  const int wv = tid >> 6;
  const int wr = wv >> 1, wc = wv & 1;

  const int srow = tid >> 2;           // staging row 0..63
  const int scol = (tid & 3) * 8;      // 0,8,16,24
  const int an   = n0 + srow;
  const bool aok = an < NB;
  const unsigned short* wbase = A.weffT + ((size_t)(p * MDIM + mo0 + srow)) * KDIM + scol;

  float4 av0, av1; ushort8 bv;

#define GLOAD(cc) {                                                               \
    int xi = g_ck.xidx[cc];                                                       \
    const float* xp = A.x[xi] + (size_t)an * g_ck.ns[cc]                          \
                      + g_ck.offc[cc] + p * CI + scol;                            \
    if (aok) { av0 = *(const float4*)xp; av1 = *(const float4*)(xp + 4); }        \
    else { av0 = make_float4(0.f,0.f,0.f,0.f); av1 = av0; }                       \
    bv = *(const ushort8*)(wbase + (size_t)(cc) * 32);                            \
  }

#define CVT_WRITE(buf) {                                                          \
    ushort8 ah;                                                                   \
    float fa[8] = {av0.x,av0.y,av0.z,av0.w,av1.x,av1.y,av1.z,av1.w};              \
    _Pragma("unroll")                                                             \
    for (int e = 0; e < 8; ++e) {                                                 \
      unsigned u = __float_as_uint(fa[e]);                                        \
      u += 0x7fff + ((u >> 16) & 1);                                              \
      ah[e] = (unsigned short)(u >> 16);                                          \
    }                                                                             \
    *(ushort8*)&sA[buf][srow][scol] = ah;                                         \
    *(ushort8*)&sB[buf][srow][scol] = bv;                                         \
  }

#define COMPUTE(buf) {                                                            \
    const int r0 = wr * 32 + (lane & 15);                                         \
    const int c0 = wc * 32 + (lane & 15);                                         \
    const int ko = (lane >> 4) * 8;                                               \
    bf16x8 a0 = *(const bf16x8*)&sA[buf][r0][ko];                                 \
    bf16x8 a1 = *(const bf16x8*)&sA[buf][r0 + 16][ko];                            \
    bf16x8 b0 = *(const bf16x8*)&sB[buf][c0][ko];                                 \
    bf16x8 b1 = *(const bf16x8*)&sB[buf][c0 + 16][ko];                            \
    acc[0][0] = __builtin_amdgcn_mfma_f32_16x16x32_bf16(a0, b0, acc[0][0], 0,0,0);\
    acc[0][1] = __builtin_amdgcn_mfma_f32_16x16x32_bf16(a0, b1, acc[0][1], 0,0,0);\
    acc[1][0] = __builtin_amdgcn_mfma_f32_16x16x32_bf16(a1, b0, acc[1][0], 0,0,0);\
    acc[1][1] = __builtin_amdgcn_mfma_f32_16x16x32_bf16(a1, b1, acc[1][1], 0,0,0);\
  }

  GLOAD(0); CVT_WRITE(0);
  __syncthreads();
  for (int cc = 0; cc < NCHUNK; ++cc) {
    const int buf = cc & 1;
    if (cc + 1 < NCHUNK) GLOAD(cc + 1);
    COMPUTE(buf);
    if (cc + 1 < NCHUNK) {
      CVT_WRITE(buf ^ 1);
      __syncthreads();
    }
  }

  // epilogue: bias + scatter. C/D: col = lane&15, row = (lane>>4)*4 + reg
  const int crow0 = n0 + wr * 32;
  const int ccol0 = mo0 + wc * 32;
  #pragma unroll
  for (int m = 0; m < 2; ++m) {
    #pragma unroll
    for (int nn = 0; nn < 2; ++nn) {
      int mo = ccol0 + nn * 16 + (lane & 15);
      int colid = mo >> 5, j = mo & 31;
      int l = g_cols.l[colid], lm = g_cols.lm[colid], cio = g_cols.ci[colid];
      long base = g_cols.obase[colid];
      float bias = A.b[2 * l + cio][(lm * PP + p) * CO + j];
      if (cio == 1 && lm == 0) bias = 0.f;
      #pragma unroll
      for (int r = 0; r < 4; ++r) {
        int n = crow0 + m * 16 + (lane >> 4) * 4 + r;
        if (n < NB)
          A.out[base + (((size_t)n * (l + 1) + lm) * PP + p) * CO + j] = acc[m][nn][r] + bias;
      }
    }
  }
#undef GLOAD
#undef CVT_WRITE
#undef COMPUTE
}

extern "C" void kernel_launch(void* const* d_in, const int* in_sizes, int n_in,
                              void* d_out, int out_size, void* d_ws, size_t ws_size,
                              hipStream_t stream) {
  float* tab = (float*)d_ws;
  float* wt  = tab + TABN;
  unsigned short* weffT = (unsigned short*)(wt + 2 * 10 * TT * PP * CI * CO);

  k_tables<<<dim3(TABN / 256), dim3(256), 0, stream>>>(tab);

  WTArgs wa;
  for (int i = 0; i < 8; ++i) wa.w[i] = (const float*)d_in[8 + i];
  wa.wt = wt;
  // largest tensor: 4*15*5*32*32 = 307200 elems -> 1200 blocks
  k_wtr<<<dim3(1200, 8), dim3(256), 0, stream>>>(wa);

  FArgs fa;
  fa.wt = wt; fa.tab = tab; fa.weffT = weffT;
  k_fold<<<dim3(MDIM, PP), dim3(256), 0, stream>>>(fa);

  GArgs ga;
  for (int i = 0; i < 8; ++i) ga.x[i] = (const float*)d_in[i];
  for (int i = 0; i < 8; ++i) ga.b[i] = (const float*)d_in[16 + i];
  ga.weffT = weffT; ga.out = (float*)d_out;
  k_gemm<<<dim3((NB + 63) / 64, MDIM / 64, PP), dim3(256), 0, stream>>>(ga);
}

// Round 3
// 372.943 us; speedup vs baseline: 3.4425x; 1.2958x over previous
//
#include <hip/hip_runtime.h>
#include <hip/hip_bf16.h>

#define NB   1000
#define NPAD 1024
#define TT   15
#define PP   5
#define CI   32
#define CO   32
#define KDIM 9600
#define MDIM 640
#define NCHUNK 300
#define NCOL   20
#define TABN  16384

typedef __attribute__((ext_vector_type(8))) short          bf16x8;
typedef __attribute__((ext_vector_type(8))) unsigned short ushort8;
typedef __attribute__((ext_vector_type(4))) float          f32x4;

// ---------------- compile-time integer maps ----------------
struct Chunks {
  short ci[NCHUNK]; short l2[NCHUNK]; short t[NCHUNK]; short k2[NCHUNK];
  short xidx[NCHUNK]; short cls[NCHUNK]; int ns[NCHUNK]; int offc[NCHUNK];
};
constexpr Chunks mkchunks() {
  Chunks c{};
  int idx = 0;
  for (int l2 = 0; l2 < 4; ++l2)
    for (int ci = 0; ci < 2; ++ci)
      for (int t = 0; t < TT; ++t)
        for (int k2 = 0; k2 <= l2; ++k2) {
          c.ci[idx] = (short)ci; c.l2[idx] = (short)l2;
          c.t[idx] = (short)t;   c.k2[idx] = (short)k2;
          c.xidx[idx] = (short)(2 * l2 + ci);
          c.cls[idx]  = (short)(l2 * (l2 + 1) / 2 + k2);
          c.ns[idx]   = TT * (l2 + 1) * PP * CI;
          c.offc[idx] = (t * (l2 + 1) + k2) * PP * CI;
          ++idx;
        }
  return c;
}
__constant__ Chunks g_ck = mkchunks();

struct Cols { int l[NCOL]; int lm[NCOL]; int ci[NCOL]; long obase[NCOL]; };
constexpr Cols mkcols() {
  Cols c{};
  long acc = 0; int idx = 0;
  for (int l = 0; l < 4; ++l)
    for (int ci = 0; ci < 2; ++ci) {
      for (int lm = 0; lm <= l; ++lm) {
        c.l[idx] = l; c.lm[idx] = lm; c.ci[idx] = ci; c.obase[idx] = acc; ++idx;
      }
      acc += (long)NB * (l + 1) * PP * CO;
    }
  return c;
}
__constant__ Cols g_cols = mkcols();

constexpr int wtsize(int tensor) { return ((tensor >> 1) + 1) * TT * PP * CI * CO; }
struct WOffs { int off[8]; int sz[8]; };
constexpr WOffs mkwoffs() {
  WOffs w{}; int acc = 0;
  for (int i = 0; i < 8; ++i) { w.off[i] = acc; w.sz[i] = wtsize(i); acc += w.sz[i]; }
  return w;
}
__constant__ WOffs g_wo = mkwoffs();

// (l1,m) pair index r=0..9 ; also reused for (l2,k2) class decode
__constant__ short g_l1of[10] = {0,1,1,2,2,2,3,3,3,3};
__constant__ short g_mof[10]  = {0,0,1,0,1,2,0,1,2,3};

// ---------------- device CG (Racah) in fp64 ----------------
__device__ double dfact(int n) { double r = 1.0; for (int i = 2; i <= n; ++i) r *= i; return r; }

__device__ double dcg(int j1, int m1, int j2, int m2, int J, int M) {
  if (m1 + m2 != M) return 0.0;
  int lo = j1 - j2; if (lo < 0) lo = -lo;
  if (J < lo || J > j1 + j2) return 0.0;
  int am1 = m1 < 0 ? -m1 : m1, am2 = m2 < 0 ? -m2 : m2, aM = M < 0 ? -M : M;
  if (am1 > j1 || am2 > j2 || aM > J) return 0.0;
  double pre = (2.0 * J + 1.0) * dfact(J + j1 - j2) * dfact(J - j1 + j2) * dfact(j1 + j2 - J)
               / dfact(j1 + j2 + J + 1);
  pre *= dfact(J + M) * dfact(J - M) * dfact(j1 - m1) * dfact(j1 + m1) * dfact(j2 - m2) * dfact(j2 + m2);
  double s = 0.0;
  for (int k = 0; k <= j1 + j2 - J; ++k) {
    int d1 = j1 + j2 - J - k, d2 = j1 - m1 - k, d3 = j2 + m2 - k,
        d4 = J - j2 + m1 + k, d5 = J - j1 - m2 + k;
    if (d1 < 0 || d2 < 0 || d3 < 0 || d4 < 0 || d5 < 0) continue;
    double den = dfact(k) * dfact(d1) * dfact(d2) * dfact(d3) * dfact(d4) * dfact(d5);
    s += ((k & 1) ? -1.0 : 1.0) / den;
  }
  return sqrt(pre) * s;
}

// tab[combo][l][l1][l2][lm][m][k2]; combos: 0 = xr*wr->r, 1 = xi*wi->r, 2 = xr*wi->i, 3 = xi*wr->i
__global__ void k_tables(float* __restrict__ tab) {
  int idx = blockIdx.x * blockDim.x + threadIdx.x;
  if (idx >= TABN) return;
  int k2 = idx & 3, m = (idx >> 2) & 3, lm = (idx >> 4) & 3, l2 = (idx >> 6) & 3,
      l1 = (idx >> 8) & 3, l = (idx >> 10) & 3, combo = (idx >> 12) & 3;
  float v = 0.f;
  int dlo = l - l1; if (dlo < 0) dlo = -dlo;
  bool valid = (lm <= l) && (m <= l1) && (k2 <= l2) && (l2 >= dlo) && (l2 <= l + l1);
  if (valid) {
    const double PI = 3.14159265358979323846;
    double coef = 8.0 * PI * PI / (2.0 * l1 + 1.0)
                  * sqrt((2.0 * l + 1.0) * (2.0 * l1 + 1.0) / (4.0 * PI * (2.0 * l2 + 1.0)))
                  * dcg(l, 0, l1, 0, l2, 0);
    double t1 = 0.0, t2 = 0.0, t3 = 0.0;
    if (k2 == lm + m)
      t1 = dcg(l, lm, l1, m, l2, k2) * ((m & 1) ? -1.0 : 1.0);
    if (m > 0 && lm - m >= 0 && k2 == lm - m)
      t2 = dcg(l, lm, l1, -m, l2, lm - m) * ((l1 & 1) ? -1.0 : 1.0);
    if (m > 0 && lm - m < 0 && k2 == m - lm)
      t3 = (((m - lm) & 1) ? -1.0 : 1.0) * (((l1 + l2) & 1) ? -1.0 : 1.0)
           * dcg(l, lm, l1, -m, l2, lm - m);
    double r = 0.0;
    if (combo == 0) r =  coef * (t1 + t2 + t3);
    else if (combo == 1) r = -coef * (t1 - t2 + t3);
    else if (combo == 2) r =  coef * (t1 - t2 - t3);
    else r = coef * (t1 + t2 - t3);
    v = (float)r;
  }
  tab[idx] = v;
}

// ---------------- weight transpose: (m,t,p,i,j) -> (m,p,j,t,i) ----------------
struct WTArgs { const float* w[8]; float* wt; };

__global__ __launch_bounds__(256) void k_wtr(WTArgs A) {
  int tensor = blockIdx.y;
  int sz = g_wo.sz[tensor];
  int e = blockIdx.x * blockDim.x + threadIdx.x;
  if (e >= sz) return;
  int i = e & 31;
  int t = (e >> 5) % TT;
  int r = e / (32 * TT);
  int j = r & 31;
  int p = (r >> 5) % PP;
  int m = r / (32 * PP);
  A.wt[g_wo.off[tensor] + e] = A.w[tensor][(((m * TT + t) * PP + p) * CI + i) * CO + j];
}

// ---------------- fold: W_effT[p][mo][k] bf16, LDS-staged ----------------
struct FArgs { const float* wt; const float* tab; unsigned short* weffT; };

__global__ __launch_bounds__(256) void k_fold(FArgs A) {
  const int tid = threadIdx.x;
  const int mo = blockIdx.x, p = blockIdx.y;
  const int j = mo & 31, col = mo >> 5;
  const int l = g_cols.l[col], lm = g_cols.lm[col], cio = g_cols.ci[col];
  __shared__ float ldsW[2][10][480];   // [wci][r=(l1,m)][t*32+i]
  __shared__ float ldsC[2][10][10];    // [ci_in][cls=(l2,k2)][r]

  for (int e = tid; e < 2 * 10 * 480; e += 256) {
    int ti = e % 480;
    int rowid = e / 480;
    int wci = rowid / 10, r = rowid % 10;
    int l1 = g_l1of[r], m = g_mof[r];
    ldsW[wci][r][ti] = A.wt[g_wo.off[2 * l1 + wci] + m * (PP * CO * TT * CI)
                            + (p * CO + j) * (TT * CI) + ti];
  }
  if (tid < 200) {
    int r = tid % 10, clk = (tid / 10) % 10, ci = tid / 100;
    int l1 = g_l1of[r], m = g_mof[r];
    int l2 = g_l1of[clk], k2 = g_mof[clk];
    int combo = cio * 2 + ci, wci = cio ^ ci;
    float v = 0.f;
    int dlo = l - l1; if (dlo < 0) dlo = -dlo;
    if (l2 >= dlo && l2 <= l + l1 && m <= l1 && k2 <= l2)
      v = A.tab[(((((combo * 4 + l) * 4 + l1) * 4 + l2) * 4 + lm) * 4 + m) * 4 + k2];
    if (wci == 1 && m == 0) v = 0.f;
    ldsC[ci][clk][r] = v;
  }
  __syncthreads();

  unsigned short* dst = A.weffT + ((size_t)(p * MDIM + mo)) * KDIM;
  for (int kk = tid; kk < KDIM; kk += 256) {
    int chunk = kk >> 5, i = kk & 31;
    int ci = g_ck.ci[chunk], t = g_ck.t[chunk], cls = g_ck.cls[chunk];
    int wci = cio ^ ci;
    float s = 0.f;
    #pragma unroll
    for (int r = 0; r < 10; ++r)
      s += ldsC[ci][cls][r] * ldsW[wci][r][t * 32 + i];
    unsigned u = __float_as_uint(s);
    u += 0x7fff + ((u >> 16) & 1);
    dst[kk] = (unsigned short)(u >> 16);
  }
}

// ---------------- xcvt: X fp32 (8 tensors) -> Xb[p][n][9600] bf16 ----------------
struct XArgs { const float* x[8]; unsigned short* xb; };

__global__ __launch_bounds__(256) void k_xcvt(XArgs A) {
  int slot = blockIdx.x * 256 + threadIdx.x;   // 6,144,000 slots of 8 bf16
  int i8 = slot % 1200;
  int rest = slot / 1200;
  int n = rest & (NPAD - 1);
  int p = rest >> 10;
  int kk = i8 * 8;
  ushort8 o;
  if (n < NB) {
    int chunk = kk >> 5;
    const float* xp = A.x[g_ck.xidx[chunk]] + (size_t)n * g_ck.ns[chunk]
                      + g_ck.offc[chunk] + p * CI + (kk & 31);
    float4 v0 = *(const float4*)xp;
    float4 v1 = *(const float4*)(xp + 4);
    float f[8] = {v0.x, v0.y, v0.z, v0.w, v1.x, v1.y, v1.z, v1.w};
    #pragma unroll
    for (int e = 0; e < 8; ++e) {
      unsigned u = __float_as_uint(f[e]);
      u += 0x7fff + ((u >> 16) & 1);
      o[e] = (unsigned short)(u >> 16);
    }
  } else {
    #pragma unroll
    for (int e = 0; e < 8; ++e) o[e] = 0;
  }
  *(ushort8*)(A.xb + ((size_t)(p * NPAD + n)) * KDIM + kk) = o;
}

// ---------------- GEMM (m97 structure): out[p] = Xb[p] (1000x9600) x WeffT[p]^T ----------------
__device__ __forceinline__ void gl_lds16(const void* g, void* l) {
  __builtin_amdgcn_global_load_lds(
      (const __attribute__((address_space(1))) unsigned int*)g,
      (__attribute__((address_space(3))) unsigned int*)l, 16, 0, 0);
}

struct GArgs { const unsigned short* xb; const unsigned short* weffT; const float* b[8]; float* out; };

__global__ __launch_bounds__(256) void k_gemm(GArgs A) {
  const int tid = threadIdx.x;
  const int lane = tid & 63;
  const int wv = tid >> 6, wr = wv >> 1, wc = wv & 1;
  const int n0 = blockIdx.x * 128, mo0 = blockIdx.y * 128, p = blockIdx.z;
  __shared__ __align__(16) unsigned short sA[128 * 64];
  __shared__ __align__(16) unsigned short sB[128 * 64];
  f32x4 acc[4][4] = {};
  const unsigned short* xbp = A.xb + (size_t)p * NPAD * KDIM;
  const unsigned short* wbp = A.weffT + (size_t)p * MDIM * KDIM;

  for (int cc = 0; cc < KDIM / 64; ++cc) {
    const int kb = cc * 64;
    #pragma unroll
    for (int u = 0; u < 4; ++u) {
      int s = u * 256 + tid;
      int row = s >> 3, kc = (s & 7) * 8;
      gl_lds16(xbp + (size_t)(n0 + row) * KDIM + kb + kc, (void*)(sA + s * 8));
      gl_lds16(wbp + (size_t)(mo0 + row) * KDIM + kb + kc, (void*)(sB + s * 8));
    }
    __syncthreads();
    #pragma unroll
    for (int ks = 0; ks < 2; ++ks) {
      const int ko = ks * 32 + (lane >> 4) * 8;
      bf16x8 af[4], bf[4];
      #pragma unroll
      for (int m = 0; m < 4; ++m)
        af[m] = *(const bf16x8*)(sA + (wr * 64 + m * 16 + (lane & 15)) * 64 + ko);
      #pragma unroll
      for (int n = 0; n < 4; ++n)
        bf[n] = *(const bf16x8*)(sB + (wc * 64 + n * 16 + (lane & 15)) * 64 + ko);
      #pragma unroll
      for (int m = 0; m < 4; ++m)
        #pragma unroll
        for (int n = 0; n < 4; ++n)
          acc[m][n] = __builtin_amdgcn_mfma_f32_16x16x32_bf16(af[m], bf[n], acc[m][n], 0, 0, 0);
    }
    __syncthreads();
  }

  // epilogue: bias + scatter. D: col = lane&15 (mo), row = (lane>>4)*4 + reg (n)
  #pragma unroll
  for (int m = 0; m < 4; ++m) {
    #pragma unroll
    for (int nn = 0; nn < 4; ++nn) {
      int mo = mo0 + wc * 64 + nn * 16 + (lane & 15);
      int colid = mo >> 5, j = mo & 31;
      int l = g_cols.l[colid], lmv = g_cols.lm[colid], cio = g_cols.ci[colid];
      long base = g_cols.obase[colid];
      float bias = A.b[2 * l + cio][(lmv * PP + p) * CO + j];
      if (cio == 1 && lmv == 0) bias = 0.f;
      #pragma unroll
      for (int r = 0; r < 4; ++r) {
        int n = n0 + wr * 64 + m * 16 + (lane >> 4) * 4 + r;
        if (n < NB)
          A.out[base + (((size_t)n * (l + 1) + lmv) * PP + p) * CO + j] = acc[m][nn][r] + bias;
      }
    }
  }
}

extern "C" void kernel_launch(void* const* d_in, const int* in_sizes, int n_in,
                              void* d_out, int out_size, void* d_ws, size_t ws_size,
                              hipStream_t stream) {
  float* tab = (float*)d_ws;                                   // 16384 f
  float* wt  = tab + TABN;                                     // 1,536,000 f
  unsigned short* weffT = (unsigned short*)(wt + 1536000);     // 30,720,000 u16
  unsigned short* xb    = weffT + (size_t)PP * MDIM * KDIM;    // 49,152,000 u16

  k_tables<<<dim3(TABN / 256), dim3(256), 0, stream>>>(tab);

  WTArgs wa;
  for (int i = 0; i < 8; ++i) wa.w[i] = (const float*)d_in[8 + i];
  wa.wt = wt;
  k_wtr<<<dim3(1200, 8), dim3(256), 0, stream>>>(wa);

  FArgs fa;
  fa.wt = wt; fa.tab = (const float*)tab; fa.weffT = weffT;
  k_fold<<<dim3(MDIM, PP), dim3(256), 0, stream>>>(fa);

  XArgs xa;
  for (int i = 0; i < 8; ++i) xa.x[i] = (const float*)d_in[i];
  xa.xb = xb;
  k_xcvt<<<dim3(24000), dim3(256), 0, stream>>>(xa);

  GArgs ga;
  ga.xb = xb; ga.weffT = weffT; ga.out = (float*)d_out;
  for (int i = 0; i < 8; ++i) ga.b[i] = (const float*)d_in[16 + i];
  k_gemm<<<dim3(8, 5, 5), dim3(256), 0, stream>>>(ga);
}

// Round 4
// 290.219 us; speedup vs baseline: 4.4237x; 1.2850x over previous
//
#include <hip/hip_runtime.h>
#include <hip/hip_bf16.h>

#define NB   1000
#define NPAD 1024
#define TT   15
#define PP   5
#define CI   32
#define CO   32
#define KDIM 9600
#define MDIM 640
#define NCHUNK 300
#define NCOL   20
#define TABN  16384
#define KSTEPS 150            // K-steps of 64

typedef __attribute__((ext_vector_type(8))) short          bf16x8;
typedef __attribute__((ext_vector_type(8))) unsigned short ushort8;
typedef __attribute__((ext_vector_type(4))) float          f32x4;

// ---------------- compile-time integer maps ----------------
struct Chunks {
  short ci[NCHUNK]; short l2[NCHUNK]; short t[NCHUNK]; short k2[NCHUNK];
  short xidx[NCHUNK]; short cls[NCHUNK]; int ns[NCHUNK]; int offc[NCHUNK];
};
constexpr Chunks mkchunks() {
  Chunks c{};
  int idx = 0;
  for (int l2 = 0; l2 < 4; ++l2)
    for (int ci = 0; ci < 2; ++ci)
      for (int t = 0; t < TT; ++t)
        for (int k2 = 0; k2 <= l2; ++k2) {
          c.ci[idx] = (short)ci; c.l2[idx] = (short)l2;
          c.t[idx] = (short)t;   c.k2[idx] = (short)k2;
          c.xidx[idx] = (short)(2 * l2 + ci);
          c.cls[idx]  = (short)(l2 * (l2 + 1) / 2 + k2);
          c.ns[idx]   = TT * (l2 + 1) * PP * CI;
          c.offc[idx] = (t * (l2 + 1) + k2) * PP * CI;
          ++idx;
        }
  return c;
}
__constant__ Chunks g_ck = mkchunks();

struct Cols { int l[NCOL]; int lm[NCOL]; int ci[NCOL]; long obase[NCOL]; };
constexpr Cols mkcols() {
  Cols c{};
  long acc = 0; int idx = 0;
  for (int l = 0; l < 4; ++l)
    for (int ci = 0; ci < 2; ++ci) {
      for (int lm = 0; lm <= l; ++lm) {
        c.l[idx] = l; c.lm[idx] = lm; c.ci[idx] = ci; c.obase[idx] = acc; ++idx;
      }
      acc += (long)NB * (l + 1) * PP * CO;
    }
  return c;
}
__constant__ Cols g_cols = mkcols();

constexpr int wtsize(int tensor) { return ((tensor >> 1) + 1) * TT * PP * CI * CO; }
struct WOffs { int off[8]; int sz[8]; };
constexpr WOffs mkwoffs() {
  WOffs w{}; int acc = 0;
  for (int i = 0; i < 8; ++i) { w.off[i] = acc; w.sz[i] = wtsize(i); acc += w.sz[i]; }
  return w;
}
__constant__ WOffs g_wo = mkwoffs();

__constant__ short g_l1of[10] = {0,1,1,2,2,2,3,3,3,3};
__constant__ short g_mof[10]  = {0,0,1,0,1,2,0,1,2,3};

// ---------------- device CG (Racah) in fp64 ----------------
__device__ double dfact(int n) { double r = 1.0; for (int i = 2; i <= n; ++i) r *= i; return r; }

__device__ double dcg(int j1, int m1, int j2, int m2, int J, int M) {
  if (m1 + m2 != M) return 0.0;
  int lo = j1 - j2; if (lo < 0) lo = -lo;
  if (J < lo || J > j1 + j2) return 0.0;
  int am1 = m1 < 0 ? -m1 : m1, am2 = m2 < 0 ? -m2 : m2, aM = M < 0 ? -M : M;
  if (am1 > j1 || am2 > j2 || aM > J) return 0.0;
  double pre = (2.0 * J + 1.0) * dfact(J + j1 - j2) * dfact(J - j1 + j2) * dfact(j1 + j2 - J)
               / dfact(j1 + j2 + J + 1);
  pre *= dfact(J + M) * dfact(J - M) * dfact(j1 - m1) * dfact(j1 + m1) * dfact(j2 - m2) * dfact(j2 + m2);
  double s = 0.0;
  for (int k = 0; k <= j1 + j2 - J; ++k) {
    int d1 = j1 + j2 - J - k, d2 = j1 - m1 - k, d3 = j2 + m2 - k,
        d4 = J - j2 + m1 + k, d5 = J - j1 - m2 + k;
    if (d1 < 0 || d2 < 0 || d3 < 0 || d4 < 0 || d5 < 0) continue;
    double den = dfact(k) * dfact(d1) * dfact(d2) * dfact(d3) * dfact(d4) * dfact(d5);
    s += ((k & 1) ? -1.0 : 1.0) / den;
  }
  return sqrt(pre) * s;
}

__global__ void k_tables(float* __restrict__ tab) {
  int idx = blockIdx.x * blockDim.x + threadIdx.x;
  if (idx >= TABN) return;
  int k2 = idx & 3, m = (idx >> 2) & 3, lm = (idx >> 4) & 3, l2 = (idx >> 6) & 3,
      l1 = (idx >> 8) & 3, l = (idx >> 10) & 3, combo = (idx >> 12) & 3;
  float v = 0.f;
  int dlo = l - l1; if (dlo < 0) dlo = -dlo;
  bool valid = (lm <= l) && (m <= l1) && (k2 <= l2) && (l2 >= dlo) && (l2 <= l + l1);
  if (valid) {
    const double PI = 3.14159265358979323846;
    double coef = 8.0 * PI * PI / (2.0 * l1 + 1.0)
                  * sqrt((2.0 * l + 1.0) * (2.0 * l1 + 1.0) / (4.0 * PI * (2.0 * l2 + 1.0)))
                  * dcg(l, 0, l1, 0, l2, 0);
    double t1 = 0.0, t2 = 0.0, t3 = 0.0;
    if (k2 == lm + m)
      t1 = dcg(l, lm, l1, m, l2, k2) * ((m & 1) ? -1.0 : 1.0);
    if (m > 0 && lm - m >= 0 && k2 == lm - m)
      t2 = dcg(l, lm, l1, -m, l2, lm - m) * ((l1 & 1) ? -1.0 : 1.0);
    if (m > 0 && lm - m < 0 && k2 == m - lm)
      t3 = (((m - lm) & 1) ? -1.0 : 1.0) * (((l1 + l2) & 1) ? -1.0 : 1.0)
           * dcg(l, lm, l1, -m, l2, lm - m);
    double r = 0.0;
    if (combo == 0) r =  coef * (t1 + t2 + t3);
    else if (combo == 1) r = -coef * (t1 - t2 + t3);
    else if (combo == 2) r =  coef * (t1 - t2 - t3);
    else r = coef * (t1 + t2 - t3);
    v = (float)r;
  }
  tab[idx] = v;
}

// ---------------- weight transpose: (m,t,p,i,j) -> (m,p,j,t,i) ----------------
struct WTArgs { const float* w[8]; float* wt; };

__global__ __launch_bounds__(256) void k_wtr(WTArgs A) {
  int tensor = blockIdx.y;
  int sz = g_wo.sz[tensor];
  int e = blockIdx.x * blockDim.x + threadIdx.x;
  if (e >= sz) return;
  int i = e & 31;
  int t = (e >> 5) % TT;
  int r = e / (32 * TT);
  int j = r & 31;
  int p = (r >> 5) % PP;
  int m = r / (32 * PP);
  A.wt[g_wo.off[tensor] + e] = A.w[tensor][(((m * TT + t) * PP + p) * CI + i) * CO + j];
}

// ---------------- fold: W_effT[p][mo][k] bf16, LDS-staged ----------------
struct FArgs { const float* wt; const float* tab; unsigned short* weffT; };

__global__ __launch_bounds__(256) void k_fold(FArgs A) {
  const int tid = threadIdx.x;
  const int mo = blockIdx.x, p = blockIdx.y;
  const int j = mo & 31, col = mo >> 5;
  const int l = g_cols.l[col], lm = g_cols.lm[col], cio = g_cols.ci[col];
  __shared__ float ldsW[2][10][480];
  __shared__ float ldsC[2][10][10];

  for (int e = tid; e < 2 * 10 * 480; e += 256) {
    int ti = e % 480;
    int rowid = e / 480;
    int wci = rowid / 10, r = rowid % 10;
    int l1 = g_l1of[r], m = g_mof[r];
    ldsW[wci][r][ti] = A.wt[g_wo.off[2 * l1 + wci] + m * (PP * CO * TT * CI)
                            + (p * CO + j) * (TT * CI) + ti];
  }
  if (tid < 200) {
    int r = tid % 10, clk = (tid / 10) % 10, ci = tid / 100;
    int l1 = g_l1of[r], m = g_mof[r];
    int l2 = g_l1of[clk], k2 = g_mof[clk];
    int combo = cio * 2 + ci, wci = cio ^ ci;
    float v = 0.f;
    int dlo = l - l1; if (dlo < 0) dlo = -dlo;
    if (l2 >= dlo && l2 <= l + l1 && m <= l1 && k2 <= l2)
      v = A.tab[(((((combo * 4 + l) * 4 + l1) * 4 + l2) * 4 + lm) * 4 + m) * 4 + k2];
    if (wci == 1 && m == 0) v = 0.f;
    ldsC[ci][clk][r] = v;
  }
  __syncthreads();

  unsigned short* dst = A.weffT + ((size_t)(p * MDIM + mo)) * KDIM;
  for (int kk = tid; kk < KDIM; kk += 256) {
    int chunk = kk >> 5, i = kk & 31;
    int ci = g_ck.ci[chunk], t = g_ck.t[chunk], cls = g_ck.cls[chunk];
    int wci = cio ^ ci;
    float s = 0.f;
    #pragma unroll
    for (int r = 0; r < 10; ++r)
      s += ldsC[ci][cls][r] * ldsW[wci][r][t * 32 + i];
    unsigned u = __float_as_uint(s);
    u += 0x7fff + ((u >> 16) & 1);
    dst[kk] = (unsigned short)(u >> 16);
  }
}

// ---------------- xcvt: X fp32 (8 tensors) -> Xb[p][n][9600] bf16 ----------------
struct XArgs { const float* x[8]; unsigned short* xb; };

__global__ __launch_bounds__(256) void k_xcvt(XArgs A) {
  int slot = blockIdx.x * 256 + threadIdx.x;
  int i8 = slot % 1200;
  int rest = slot / 1200;
  int n = rest & (NPAD - 1);
  int p = rest >> 10;
  int kk = i8 * 8;
  ushort8 o;
  if (n < NB) {
    int chunk = kk >> 5;
    const float* xp = A.x[g_ck.xidx[chunk]] + (size_t)n * g_ck.ns[chunk]
                      + g_ck.offc[chunk] + p * CI + (kk & 31);
    float4 v0 = *(const float4*)xp;
    float4 v1 = *(const float4*)(xp + 4);
    float f[8] = {v0.x, v0.y, v0.z, v0.w, v1.x, v1.y, v1.z, v1.w};
    #pragma unroll
    for (int e = 0; e < 8; ++e) {
      unsigned u = __float_as_uint(f[e]);
      u += 0x7fff + ((u >> 16) & 1);
      o[e] = (unsigned short)(u >> 16);
    }
  } else {
    #pragma unroll
    for (int e = 0; e < 8; ++e) o[e] = 0;
  }
  *(ushort8*)(A.xb + ((size_t)(p * NPAD + n)) * KDIM + kk) = o;
}

// ---------------- GEMM split-K: partial[p,sp] = Xb[p] x WeffT[p]^T over K-slice ----------------
__device__ __forceinline__ void gl_lds16(const void* g, void* l) {
  __builtin_amdgcn_global_load_lds(
      (const __attribute__((address_space(1))) unsigned int*)g,
      (__attribute__((address_space(3))) unsigned int*)l, 16, 0, 0);
}

struct GArgs { const unsigned short* xb; const unsigned short* weffT; float* partial; int nsplit; };

__global__ __launch_bounds__(256) void k_gemm(GArgs A) {
  const int tid = threadIdx.x;
  const int lane = tid & 63;
  const int wv = tid >> 6, wr = wv >> 1, wc = wv & 1;
  const int n0 = blockIdx.x * 128, mo0 = blockIdx.y * 128;
  const int zz = blockIdx.z;
  const int NS = A.nsplit;
  const int p = zz / NS, sp = zz % NS;
  const int bsteps = KSTEPS / NS, rem = KSTEPS % NS;
  const int mysteps = bsteps + (sp < rem ? 1 : 0);
  const int sstart = sp * bsteps + (sp < rem ? sp : rem);

  __shared__ __align__(16) unsigned short sA[128 * 64];
  __shared__ __align__(16) unsigned short sB[128 * 64];
  f32x4 acc[4][4] = {};
  const unsigned short* xbp = A.xb + (size_t)p * NPAD * KDIM;
  const unsigned short* wbp = A.weffT + (size_t)p * MDIM * KDIM;

  for (int cc = 0; cc < mysteps; ++cc) {
    const int kb = (sstart + cc) * 64;
    // staging: linear LDS dest, inverse-swizzled global source (rule #21)
    #pragma unroll
    for (int u = 0; u < 4; ++u) {
      int s = u * 256 + tid;
      int row = s >> 3;
      int qs = (s & 7) ^ (row & 7);          // pre-swizzled 16B slot
      gl_lds16(xbp + (size_t)(n0 + row) * KDIM + kb + qs * 8, (void*)(sA + s * 8));
      gl_lds16(wbp + (size_t)(mo0 + row) * KDIM + kb + qs * 8, (void*)(sB + s * 8));
    }
    __syncthreads();
    #pragma unroll
    for (int ks = 0; ks < 2; ++ks) {
      const int q = ks * 4 + (lane >> 4);    // logical 16B slot 0..7
      bf16x8 af[4], bfr[4];
      #pragma unroll
      for (int m = 0; m < 4; ++m) {
        int ra = wr * 64 + m * 16 + (lane & 15);
        af[m] = *(const bf16x8*)(sA + ra * 64 + ((q ^ (ra & 7)) << 3));
      }
      #pragma unroll
      for (int n = 0; n < 4; ++n) {
        int rb = wc * 64 + n * 16 + (lane & 15);
        bfr[n] = *(const bf16x8*)(sB + rb * 64 + ((q ^ (rb & 7)) << 3));
      }
      #pragma unroll
      for (int m = 0; m < 4; ++m)
        #pragma unroll
        for (int n = 0; n < 4; ++n)
          acc[m][n] = __builtin_amdgcn_mfma_f32_16x16x32_bf16(af[m], bfr[n], acc[m][n], 0, 0, 0);
    }
    __syncthreads();
  }

  // write raw fp32 partial tile. D: col = lane&15 (mo), row = (lane>>4)*4 + r (n)
  float* pout = A.partial + (size_t)zz * (NPAD * MDIM);
  #pragma unroll
  for (int m = 0; m < 4; ++m) {
    #pragma unroll
    for (int nn = 0; nn < 4; ++nn) {
      int mo = mo0 + wc * 64 + nn * 16 + (lane & 15);
      #pragma unroll
      for (int r = 0; r < 4; ++r) {
        int n = n0 + wr * 64 + m * 16 + (lane >> 4) * 4 + r;
        pout[(size_t)n * MDIM + mo] = acc[m][nn][r];
      }
    }
  }
}

// ---------------- reduce + bias + scatter ----------------
struct RArgs { const float* partial; const float* b[8]; float* out; int nsplit; };

__global__ __launch_bounds__(256) void k_red(RArgs A) {
  int e = blockIdx.x * 256 + threadIdx.x;
  if (e >= NB * MDIM * PP) return;
  int mo = e % MDIM;
  int rest = e / MDIM;
  int n = rest % NB;
  int p = rest / NB;
  float s = 0.f;
  for (int sp = 0; sp < A.nsplit; ++sp)
    s += A.partial[((size_t)(p * A.nsplit + sp) * NPAD + n) * MDIM + mo];
  int colid = mo >> 5, j = mo & 31;
  int l = g_cols.l[colid], lmv = g_cols.lm[colid], cio = g_cols.ci[colid];
  long base = g_cols.obase[colid];
  float bias = A.b[2 * l + cio][(lmv * PP + p) * CO + j];
  if (cio == 1 && lmv == 0) bias = 0.f;
  A.out[base + (((size_t)n * (l + 1) + lmv) * PP + p) * CO + j] = s + bias;
}

extern "C" void kernel_launch(void* const* d_in, const int* in_sizes, int n_in,
                              void* d_out, int out_size, void* d_ws, size_t ws_size,
                              hipStream_t stream) {
  float* tab = (float*)d_ws;                                   // 16384 f
  float* wt  = tab + TABN;                                     // 1,536,000 f
  unsigned short* weffT = (unsigned short*)(wt + 1536000);     // 30,720,000 u16
  unsigned short* xb    = weffT + (size_t)PP * MDIM * KDIM;    // 49,152,000 u16
  float* partial = (float*)(xb + (size_t)PP * NPAD * KDIM);

  size_t base_bytes = (size_t)TABN * 4 + 1536000ull * 4
                    + (size_t)PP * MDIM * KDIM * 2 + (size_t)PP * NPAD * KDIM * 2;
  size_t per_split = (size_t)PP * NPAD * MDIM * 4;             // 13.1 MB
  int NS = 1;
  for (int c = 4; c >= 2; --c)
    if (ws_size >= base_bytes + (size_t)c * per_split) { NS = c; break; }

  k_tables<<<dim3(TABN / 256), dim3(256), 0, stream>>>(tab);

  WTArgs wa;
  for (int i = 0; i < 8; ++i) wa.w[i] = (const float*)d_in[8 + i];
  wa.wt = wt;
  k_wtr<<<dim3(1200, 8), dim3(256), 0, stream>>>(wa);

  FArgs fa;
  fa.wt = wt; fa.tab = (const float*)tab; fa.weffT = weffT;
  k_fold<<<dim3(MDIM, PP), dim3(256), 0, stream>>>(fa);

  XArgs xa;
  for (int i = 0; i < 8; ++i) xa.x[i] = (const float*)d_in[i];
  xa.xb = xb;
  k_xcvt<<<dim3(24000), dim3(256), 0, stream>>>(xa);

  GArgs ga;
  ga.xb = xb; ga.weffT = weffT; ga.partial = partial; ga.nsplit = NS;
  k_gemm<<<dim3(8, 5, 5 * NS), dim3(256), 0, stream>>>(ga);

  RArgs ra;
  ra.partial = partial; ra.out = (float*)d_out; ra.nsplit = NS;
  for (int i = 0; i < 8; ++i) ra.b[i] = (const float*)d_in[16 + i];
  k_red<<<dim3((NB * MDIM * PP + 255) / 256), dim3(256), 0, stream>>>(ra);
}